// Round 11
// baseline (367.559 us; speedup 1.0000x reference)
//
#include <hip/hip_runtime.h>
#include <hip/hip_fp16.h>
#include <cstdint>
#include <cstddef>

// Problem constants (match reference setup_inputs)
#define NN   50000      // nodes  (< 65536: src/dst fit 16 bits)
#define NE   1200000    // edges
#define NR   45         // relations
#define INC  64
#define HIDC 32
#define OUTC 16
// Padded edge capacity: each relation bucket padded to multiple of 64 so every
// wave's 64 edges share one relation. NE + NR*64, itself a multiple of 64.
#define MAXE 1202880
#define NCHUNK (MAXE/64)
// relation counting-sort blocking
#define EPB 4096
#define NB  ((NE + EPB - 1) / EPB)      // 293 blocks
#define SEG 16                          // scan segments per relation
#define BPS ((NB + SEG - 1) / SEG)      // 19 blocks per segment
// relcnt LDS: 16000 words x two 16-bit counters = 32000 dsts per half
#define HALFW 16000
#define HALFD (2 * HALFW)
// LDS row strides (f32 words) for the MFMA epilogue transpose
#define MS1 34
#define MS2 18

typedef _Float16 f16x8 __attribute__((ext_vector_type(8)));
typedef float    f32x4 __attribute__((ext_vector_type(4)));

union F16Bits { unsigned short u; _Float16 f; };
union ABFrag   { uint4 u; f16x8 f; };

// ---------------------------------------------------------------------------
// Fused prep + relation histogram. All blocks do striped prep work (MFMA
// B-fragments in exact lane order + x f32->f16 cast); the first NB blocks
// also build the per-block 45-bin relation histogram (LDS atomics only).
//   B[k][n] fragment for 16x16x32: lane holds k=(lane>>4)*8+j, n=lane&15.
__global__ __launch_bounds__(256) void preph_k(const float* __restrict__ W1,
                                               const float* __restrict__ W2,
                                               const float* __restrict__ x,
                                               const int* __restrict__ ei,
                                               const int* __restrict__ et,
                                               __half* __restrict__ W1f,
                                               __half* __restrict__ W2f,
                                               __half* __restrict__ xh,
                                               unsigned* __restrict__ ghist) {
    __shared__ unsigned lh[NR];
    int t = threadIdx.x, b = blockIdx.x;
    if (t < NR) lh[t] = 0;
    __syncthreads();
    if (b < NB) {
        #pragma unroll
        for (int it = 0; it < EPB / 256; ++it) {
            int e = b * EPB + it * 256 + t;
            if (e < NE) {
                int r = et[e], src = ei[e], dst = ei[NE + e];
                if ((unsigned)r < NR && (unsigned)src < NN && (unsigned)dst < NN)
                    atomicAdd(&lh[r], 1u);
            }
        }
    }
    __syncthreads();
    if (b < NB && t < NR) ghist[b * NR + t] = lh[t];
    int g = b * 256 + t;
    if (g < NR * 2048) {
        int r = g >> 11, rem = g & 2047;
        int kb = rem >> 10, nb = (rem >> 9) & 1;
        int lane = (rem >> 3) & 63, j = rem & 7;
        int k = kb * 32 + (lane >> 4) * 8 + j;
        int n = nb * 16 + (lane & 15);
        W1f[g] = __float2half(W1[(r * INC + k) * HIDC + n]);
    }
    if (g < NR * 512) {
        int r = g >> 9, rem = g & 511;
        int lane = (rem >> 3) & 63, j = rem & 7;
        int k = (lane >> 4) * 8 + j;
        int n = lane & 15;
        W2f[g] = __float2half(W2[(r * HIDC + k) * OUTC + n]);
    }
    if (g < NN * INC / 2) {
        float2 f = ((const float2*)x)[g];
        union { __half2 h; unsigned u; } cv;
        cv.h = __floats2half2_rn(f.x, f.y);
        ((unsigned*)xh)[g] = cv.u;
    }
}

// Single block: exclusive prefix within each relation via two-pass segmented
// scan, 64-padded relation bases, per-(r,block) scatter bases, relation
// ranges, chunk->relation via parallel binary search.
__global__ __launch_bounds__(1024) void rscan_k(unsigned* __restrict__ ghist,
                                                unsigned* __restrict__ rbase,
                                                unsigned* __restrict__ rngs,
                                                int* __restrict__ chunkrel) {
    __shared__ unsigned part[NR * SEG];
    __shared__ unsigned relbase[NR + 1];
    __shared__ unsigned reltot[NR];
    int t = threadIdx.x;
    int r = t / SEG, sg = t % SEG;
    if (t < NR * SEG) {
        unsigned s = 0;
        int b0 = sg * BPS, b1 = b0 + BPS; if (b1 > NB) b1 = NB;
        for (int b = b0; b < b1; ++b) s += ghist[b * NR + r];
        part[t] = s;
    }
    __syncthreads();
    if (t < NR) {
        unsigned run = 0;
        #pragma unroll
        for (int s = 0; s < SEG; ++s) {
            unsigned v = part[t * SEG + s];
            part[t * SEG + s] = run;
            run += v;
        }
        reltot[t] = run;
    }
    __syncthreads();
    if (t == 0) {
        unsigned acc = 0;
        for (int rr = 0; rr < NR; ++rr) {
            relbase[rr] = acc;
            acc += ((reltot[rr] + 63u) >> 6) << 6;
        }
        relbase[NR] = acc;
    }
    __syncthreads();
    if (t < NR * SEG) {
        unsigned run = part[t];
        int b0 = sg * BPS, b1 = b0 + BPS; if (b1 > NB) b1 = NB;
        for (int b = b0; b < b1; ++b) {
            unsigned v = ghist[b * NR + r];
            ghist[b * NR + r] = run;
            run += v;
        }
    }
    __syncthreads();
    for (int i = t; i < NR * NB; i += 1024) {
        int rr = i / NB, b = i % NB;
        rbase[i] = ghist[b * NR + rr] + relbase[rr];
    }
    if (t < NR) {
        rngs[2 * t]     = relbase[t];
        rngs[2 * t + 1] = relbase[t] + reltot[t];
    }
    for (int c = t; c < NCHUNK; c += 1024) {
        unsigned pos = (unsigned)c << 6;
        int lo = 0, hi = NR - 1;
        while (lo < hi) {
            int mid = (lo + hi + 1) >> 1;
            if (relbase[mid] <= pos) lo = mid; else hi = mid - 1;
        }
        chunkrel[c] = lo;
    }
}

// Deterministic scatter into relation buckets (LDS atomics only).
// rsorted[pos] = {dst:16 | src:16}. Pad slots keep 0xFFFFFFFF (dst sentinel).
__global__ __launch_bounds__(256) void rscatter_k(const int* __restrict__ ei,
                                                  const int* __restrict__ et,
                                                  const unsigned* __restrict__ rbase,
                                                  unsigned* __restrict__ rsorted) {
    __shared__ unsigned lbase[NR], lcur[NR];
    int t = threadIdx.x, b = blockIdx.x;
    if (t < NR) { lbase[t] = rbase[t * NB + b]; lcur[t] = 0; }
    __syncthreads();
    #pragma unroll
    for (int it = 0; it < EPB / 256; ++it) {
        int e = b * EPB + it * 256 + t;
        if (e < NE) {
            int r = et[e], src = ei[e], dst = ei[NE + e];
            if ((unsigned)r < NR && (unsigned)src < NN && (unsigned)dst < NN) {
                unsigned local = atomicAdd(&lcur[r], 1u);
                rsorted[lbase[r] + local] = (unsigned)src | ((unsigned)dst << 16);
            }
        }
    }
}

// Per-relation dst counts + per-edge rank, all in LDS (two packed u16
// counters per word). One block = one (relation, dst-half) pair -> grid 2*NR.
__global__ __launch_bounds__(1024) void relcnt_k(const unsigned* __restrict__ rsorted,
                                                 const unsigned* __restrict__ rngs,
                                                 unsigned* __restrict__ cnt,
                                                 unsigned short* __restrict__ rank16) {
    __shared__ unsigned lds[HALFW];     // 64000 B
    int r = blockIdx.x >> 1, half = blockIdx.x & 1, t = threadIdx.x;
    unsigned base = rngs[2 * r], end = rngs[2 * r + 1];
    unsigned dlo = half * HALFD;
    unsigned dhi = (dlo + HALFD < NN) ? (dlo + HALFD) : NN;
    for (int w = t; w < HALFW; w += 1024) lds[w] = 0;
    __syncthreads();
    for (unsigned s = base + t; s < end; s += 1024) {
        unsigned d = rsorted[s] >> 16;
        if (d >= dlo && d < dhi) {
            unsigned off = d - dlo;
            atomicAdd(&lds[off >> 1], (off & 1) ? 0x10000u : 1u);
        }
    }
    __syncthreads();
    for (int w = t; w < HALFW; w += 1024) {
        unsigned u = lds[w];
        unsigned d0 = dlo + 2 * w;
        if (d0 < dhi) cnt[(size_t)r * NN + d0] = u & 0xFFFFu;
        unsigned d1 = d0 + 1;
        if (d1 < dhi) cnt[(size_t)r * NN + d1] = u >> 16;
    }
    __syncthreads();
    for (int w = t; w < HALFW; w += 1024) lds[w] = 0;
    __syncthreads();
    for (unsigned s = base + t; s < end; s += 1024) {
        unsigned d = rsorted[s] >> 16;
        if (d >= dlo && d < dhi) {
            unsigned off = d - dlo;
            unsigned old = atomicAdd(&lds[off >> 1], (off & 1) ? 0x10000u : 1u);
            rank16[s] = (unsigned short)((off & 1) ? (old >> 16) : (old & 0xFFFFu));
        }
    }
}

// Per-dst: relation-prefix offsets + f16 inverse counts, packed one word per
// (r,dst): {reloff:16 | f16(1/cnt):16}. Also derives dhist[dst] = degree.
__global__ __launch_bounds__(256) void drel_k(const unsigned* __restrict__ cnt,
                                              unsigned* __restrict__ packed,
                                              unsigned* __restrict__ dhist) {
    int dst = blockIdx.x * 256 + threadIdx.x;
    if (dst >= NN) return;
    unsigned run = 0;
    #pragma unroll 5
    for (int r = 0; r < NR; ++r) {
        unsigned c = cnt[(size_t)r * NN + dst];
        F16Bits fb; fb.f = (_Float16)(c ? 1.0f / (float)c : 0.0f);
        packed[(size_t)r * NN + dst] = (run & 0xFFFFu) | ((unsigned)fb.u << 16);
        run += c;
    }
    dhist[dst] = run;
}

// Exclusive prefix over NN dst bins -> rowptr[NN+1] (tiled block scan).
__global__ __launch_bounds__(1024) void dprefix_k(const unsigned* __restrict__ dhist,
                                                  unsigned* __restrict__ rowptr) {
    __shared__ unsigned wsum[16];
    __shared__ unsigned carry_s;
    int t = threadIdx.x;
    int lane = t & 63, wv = t >> 6;
    if (t == 0) carry_s = 0;
    __syncthreads();
    for (int base = 0; base < NN; base += 1024) {
        int i = base + t;
        unsigned v = (i < NN) ? dhist[i] : 0u;
        unsigned s = v;
        #pragma unroll
        for (int off = 1; off < 64; off <<= 1) {
            unsigned n = __shfl_up(s, off);
            if (lane >= off) s += n;
        }
        if (lane == 63) wsum[wv] = s;
        __syncthreads();
        if (wv == 0) {
            unsigned ws = (lane < 16) ? wsum[lane] : 0u;
            #pragma unroll
            for (int off = 1; off < 16; off <<= 1) {
                unsigned n = __shfl_up(ws, off);
                if (lane >= off) ws += n;
            }
            if (lane < 16) wsum[lane] = ws;
        }
        __syncthreads();
        unsigned waveoff = (wv == 0) ? 0u : wsum[wv - 1];
        unsigned carry = carry_s;
        if (i < NN) rowptr[i] = carry + waveoff + s - v;
        __syncthreads();
        if (t == 1023) carry_s = carry + wsum[15];
        __syncthreads();
    }
    if (t == 0) rowptr[NN] = carry_s;
}

// ---------------------------------------------------------------------------
// Shared per-edge preamble for the msg kernels (finalize folded in):
// rel from chunkrel (wave-uniform), dst/src from rsorted, scale+reloff from
// packed (L2-resident 200 KB plane per relation), dpos = rowptr+reloff+rank.
#define EDGE_PREAMBLE(OUT_REL, OUT_SRC, OUT_SC, OUT_DROW)                      \
    int OUT_REL = __builtin_amdgcn_readfirstlane(chunkrel[wave]);              \
    unsigned v_ = rsorted[e];                                                  \
    unsigned dst_ = v_ >> 16;                                                  \
    bool valid_ = dst_ < NN;                                                   \
    unsigned d2_ = valid_ ? dst_ : 0u;                                         \
    unsigned pk_ = packed[(size_t)OUT_REL * NN + d2_];                         \
    unsigned rp_ = rowptr[d2_];                                                \
    F16Bits fb_; fb_.u = valid_ ? (unsigned short)(pk_ >> 16) : (unsigned short)0; \
    float OUT_SC = (float)fb_.f;                                               \
    int OUT_SRC = valid_ ? (int)(v_ & 0xFFFFu) : 0;                            \
    int OUT_DROW = valid_ ? (int)(rp_ + (pk_ & 0xFFFFu) + (unsigned)rank16[e]) : NE;

// Layer-1 messages via MFMA. One wave = 64 edges of ONE relation = 4 tiles of
// 16 edges; 4x mfma_f32_16x16x32_f16 per tile vs wave-uniform precomputed B
// fragments; C transposed through a per-tile 16-row LDS buffer; rows written
// f16 (64 B) at DST-SORTED slots so gathers read sequentially.
// (fp8 rows tried in R10: absmax 0.190 > 0.159 threshold — reverted.)
__global__ __launch_bounds__(256) void msg1_k(const __half* __restrict__ xh,
                                              const __half* __restrict__ W1f,
                                              const unsigned* __restrict__ rsorted,
                                              const unsigned short* __restrict__ rank16,
                                              const unsigned* __restrict__ packed,
                                              const unsigned* __restrict__ rowptr,
                                              const int* __restrict__ chunkrel,
                                              __half* __restrict__ msg) {
    __shared__ float lmsg[4 * 16 * MS1];    // 8704 B
    int tid = threadIdx.x;
    int wv = tid >> 6, lane = tid & 63;
    int wave = (blockIdx.x * 256 + tid) >> 6;
    if (wave >= NCHUNK) return;
    int e = (wave << 6) + lane;
    EDGE_PREAMBLE(rel, src, sc, drow)
    const uint4* __restrict__ wf = (const uint4*)W1f + (size_t)rel * 256;
    ABFrag b00, b01, b10, b11;
    b00.u = wf[0 * 64 + lane];
    b01.u = wf[1 * 64 + lane];
    b10.u = wf[2 * 64 + lane];
    b11.u = wf[3 * 64 + lane];
    int quad = lane >> 4, col = lane & 15;
    float* __restrict__ lwave = lmsg + wv * (16 * MS1);
    #pragma unroll
    for (int tl = 0; tl < 4; ++tl) {
        int s = __shfl(src, tl * 16 + col);
        const uint4* __restrict__ xp = (const uint4*)(xh + (size_t)s * INC) + quad;
        ABFrag a0, a1;
        a0.u = xp[0];
        a1.u = xp[4];
        f32x4 acc0 = {0.f, 0.f, 0.f, 0.f}, acc1 = {0.f, 0.f, 0.f, 0.f};
        acc0 = __builtin_amdgcn_mfma_f32_16x16x32_f16(a0.f, b00.f, acc0, 0, 0, 0);
        acc0 = __builtin_amdgcn_mfma_f32_16x16x32_f16(a1.f, b10.f, acc0, 0, 0, 0);
        acc1 = __builtin_amdgcn_mfma_f32_16x16x32_f16(a0.f, b01.f, acc1, 0, 0, 0);
        acc1 = __builtin_amdgcn_mfma_f32_16x16x32_f16(a1.f, b11.f, acc1, 0, 0, 0);
        float* __restrict__ lt = lwave + (quad * 4) * MS1;
        #pragma unroll
        for (int i = 0; i < 4; ++i) {
            lt[i * MS1 + col]      = acc0[i];
            lt[i * MS1 + col + 16] = acc1[i];
        }
        if ((lane >> 4) == tl) {
            const float* __restrict__ myrow = lwave + (lane & 15) * MS1;
            unsigned um[16];
            #pragma unroll
            for (int k = 0; k < 16; ++k) {
                float2 vv = *(const float2*)(myrow + 2 * k);
                union { __half2 h; unsigned u; } cv;
                cv.h = __floats2half2_rn(vv.x * sc, vv.y * sc);
                um[k] = cv.u;
            }
            uint4* __restrict__ mrow = (uint4*)(msg + (size_t)drow * HIDC);
            #pragma unroll
            for (int q = 0; q < 4; ++q)
                mrow[q] = make_uint4(um[4*q], um[4*q+1], um[4*q+2], um[4*q+3]);
        }
    }
}

// Layer-2 messages via MFMA (32 -> 16): 1 MFMA per 16-edge tile, f16 rows.
__global__ __launch_bounds__(256) void msg2_k(const __half* __restrict__ hh,
                                              const __half* __restrict__ W2f,
                                              const unsigned* __restrict__ rsorted,
                                              const unsigned short* __restrict__ rank16,
                                              const unsigned* __restrict__ packed,
                                              const unsigned* __restrict__ rowptr,
                                              const int* __restrict__ chunkrel,
                                              __half* __restrict__ msg) {
    __shared__ float lmsg[4 * 16 * MS2];    // 4608 B
    int tid = threadIdx.x;
    int wv = tid >> 6, lane = tid & 63;
    int wave = (blockIdx.x * 256 + tid) >> 6;
    if (wave >= NCHUNK) return;
    int e = (wave << 6) + lane;
    EDGE_PREAMBLE(rel, src, sc, drow)
    ABFrag bf;
    bf.u = ((const uint4*)W2f + (size_t)rel * 64)[lane];
    int quad = lane >> 4, col = lane & 15;
    float* __restrict__ lwave = lmsg + wv * (16 * MS2);
    #pragma unroll
    for (int tl = 0; tl < 4; ++tl) {
        int s = __shfl(src, tl * 16 + col);
        ABFrag a;
        a.u = *((const uint4*)(hh + (size_t)s * HIDC) + quad);
        f32x4 acc = {0.f, 0.f, 0.f, 0.f};
        acc = __builtin_amdgcn_mfma_f32_16x16x32_f16(a.f, bf.f, acc, 0, 0, 0);
        float* __restrict__ lt = lwave + (quad * 4) * MS2;
        #pragma unroll
        for (int i = 0; i < 4; ++i) lt[i * MS2 + col] = acc[i];
        if ((lane >> 4) == tl) {
            const float* __restrict__ myrow = lwave + (lane & 15) * MS2;
            unsigned um[8];
            #pragma unroll
            for (int k = 0; k < 8; ++k) {
                float2 vv = *(const float2*)(myrow + 2 * k);
                union { __half2 h; unsigned u; } cv;
                cv.h = __floats2half2_rn(vv.x * sc, vv.y * sc);
                um[k] = cv.u;
            }
            uint4* __restrict__ mrow = (uint4*)(msg + (size_t)drow * OUTC);
            mrow[0] = make_uint4(um[0], um[1], um[2], um[3]);
            mrow[1] = make_uint4(um[4], um[5], um[6], um[7]);
        }
    }
}

// ---------------------------------------------------------------------------
// Fused gather + node update 1: h = relu(sum(msg rows) + x @ root1 + b1), f16
// out. One wave per node; msg rows contiguous (dst-sorted).
__global__ __launch_bounds__(256) void gather1_k(const float* __restrict__ x,
                                                 const float* __restrict__ root1,
                                                 const float* __restrict__ b1,
                                                 const __half* __restrict__ msg,
                                                 const unsigned* __restrict__ rowptr,
                                                 __half* __restrict__ hh) {
    __shared__ float sr[INC * HIDC];   // 8 KB, [in][c]
    for (int k = threadIdx.x; k < INC * HIDC; k += 256) sr[k] = root1[k];
    __syncthreads();
    int wid = (blockIdx.x * 256 + threadIdx.x) >> 6;   // node id; grid exact
    int lane = threadIdx.x & 63;
    int c2 = lane & 15, sub = lane >> 4;
    unsigned k0 = rowptr[wid], k1 = rowptr[wid + 1];
    float accx = 0.f, accy = 0.f;
    for (unsigned k = k0 + sub; k < k1; k += 4) {
        union { __half2 hh2; unsigned u; } cv;
        cv.u = ((const unsigned*)(msg + (size_t)k * HIDC))[c2];
        float2 f = __half22float2(cv.hh2);
        accx += f.x; accy += f.y;
    }
    const float4* __restrict__ xp = (const float4*)(x + (size_t)wid * INC + sub * 16);
    #pragma unroll
    for (int q = 0; q < 4; ++q) {
        float4 xr = xp[q];
        const float* xs = (const float*)&xr;
        #pragma unroll
        for (int j = 0; j < 4; ++j) {
            int in = sub * 16 + q * 4 + j;
            float2 rt = *(const float2*)&sr[in * HIDC + 2 * c2];
            accx = fmaf(xs[j], rt.x, accx);
            accy = fmaf(xs[j], rt.y, accy);
        }
    }
    accx += __shfl_xor(accx, 16); accy += __shfl_xor(accy, 16);
    accx += __shfl_xor(accx, 32); accy += __shfl_xor(accy, 32);
    if (sub == 0) {
        float2 bb = *(const float2*)&b1[2 * c2];
        float vx = accx + bb.x, vy = accy + bb.y;
        union { __half2 h2; unsigned u; } cv;
        cv.h2 = __floats2half2_rn(vx > 0.f ? vx : 0.f, vy > 0.f ? vy : 0.f);
        ((unsigned*)hh)[(size_t)wid * (HIDC / 2) + c2] = cv.u;
    }
}

// Fused gather + node update 2: out = sum(msg rows) + h @ root2 + b2 (f32 out).
__global__ __launch_bounds__(256) void gather2_k(const __half* __restrict__ hh,
                                                 const float* __restrict__ root2,
                                                 const float* __restrict__ b2,
                                                 const __half* __restrict__ msg,
                                                 const unsigned* __restrict__ rowptr,
                                                 float* __restrict__ out) {
    __shared__ float sr[HIDC * OUTC];  // 2 KB, [in][c]
    for (int k = threadIdx.x; k < HIDC * OUTC; k += 256) sr[k] = root2[k];
    __syncthreads();
    int wid = (blockIdx.x * 256 + threadIdx.x) >> 6;
    int lane = threadIdx.x & 63;
    int c2 = lane & 7, sub = lane >> 3;   // 8 streams
    unsigned k0 = rowptr[wid], k1 = rowptr[wid + 1];
    float accx = 0.f, accy = 0.f;
    for (unsigned k = k0 + sub; k < k1; k += 8) {
        union { __half2 hh2; unsigned u; } cv;
        cv.u = ((const unsigned*)(msg + (size_t)k * OUTC))[c2];
        float2 f = __half22float2(cv.hh2);
        accx += f.x; accy += f.y;
    }
    uint2 hw = *(const uint2*)(hh + (size_t)wid * HIDC + sub * 4);
    union { __half2 h2; unsigned u; } ca, cb;
    ca.u = hw.x; cb.u = hw.y;
    float2 ha = __half22float2(ca.h2), hb = __half22float2(cb.h2);
    float hs[4] = { ha.x, ha.y, hb.x, hb.y };
    #pragma unroll
    for (int j = 0; j < 4; ++j) {
        int in = sub * 4 + j;
        float2 rt = *(const float2*)&sr[in * OUTC + 2 * c2];
        accx = fmaf(hs[j], rt.x, accx);
        accy = fmaf(hs[j], rt.y, accy);
    }
    accx += __shfl_xor(accx, 8);  accy += __shfl_xor(accy, 8);
    accx += __shfl_xor(accx, 16); accy += __shfl_xor(accy, 16);
    accx += __shfl_xor(accx, 32); accy += __shfl_xor(accy, 32);
    if (sub == 0) {
        float2 bb = *(const float2*)&b2[2 * c2];
        *(float2*)&out[(size_t)wid * OUTC + 2 * c2] =
            make_float2(accx + bb.x, accy + bb.y);
    }
}

// ---------------------------------------------------------------------------
extern "C" void kernel_launch(void* const* d_in, const int* in_sizes, int n_in,
                              void* d_out, int out_size, void* d_ws, size_t ws_size,
                              hipStream_t stream) {
    const float* x     = (const float*)d_in[0];
    const int*   ei    = (const int*)d_in[1];   // [2, NE]
    const int*   et    = (const int*)d_in[2];   // [NE]
    const float* W1    = (const float*)d_in[3];
    const float* root1 = (const float*)d_in[4];
    const float* b1    = (const float*)d_in[5];
    const float* W2    = (const float*)d_in[6];
    const float* root2 = (const float*)d_in[7];
    const float* b2    = (const float*)d_in[8];
    float* out = (float*)d_out;

    char* ws = (char*)d_ws;
    size_t o = 0;
    auto alloc = [&](size_t bytes) -> char* {
        char* p = ws + o;
        o = (o + bytes + 255) & ~(size_t)255;
        return p;
    };
    // rsorted FIRST: single 0xFF memset marks all slots as pads (dst=0xFFFF);
    // rscatter_k overwrites exactly the NE real slots. NOTHING needs zeroing.
    unsigned* rsorted = (unsigned*)alloc((size_t)MAXE * 4);        // 4.8 MB
    size_t ff_bytes = o;
    unsigned* ghist   = (unsigned*)alloc((size_t)NR * NB * 4);
    unsigned* rbase   = (unsigned*)alloc((size_t)NR * NB * 4);
    unsigned* rngs    = (unsigned*)alloc((size_t)NR * 2 * 4);
    int*      chunkrel= (int*)     alloc((size_t)NCHUNK * 4);
    unsigned short* rank16 = (unsigned short*)alloc((size_t)MAXE * 2);
    unsigned* cnt     = (unsigned*)alloc((size_t)NR * NN * 4);     // 9.0 MB
    unsigned* packed  = (unsigned*)alloc((size_t)NR * NN * 4);     // 9.0 MB
    unsigned* dhist   = (unsigned*)alloc((size_t)NN * 4);
    unsigned* rowptr  = (unsigned*)alloc(((size_t)NN + 1) * 4);
    __half*   W1f     = (__half*)  alloc((size_t)NR * 2048 * 2);
    __half*   W2f     = (__half*)  alloc((size_t)NR * 512 * 2);
    __half*   xh      = (__half*)  alloc((size_t)NN * INC * 2);    // 6.4 MB
    __half*   hh      = (__half*)  alloc((size_t)NN * HIDC * 2);   // 3.2 MB
    // msg buffers alias: msg1 (f16, 64-B rows) fully consumed by gather1
    // before msg2 (f16, 32-B rows) is produced.
    char*     msgraw  = alloc(((size_t)NE + 1) * 64);              // 76.9 MB
    __half*   msg1    = (__half*)msgraw;
    __half*   msg2    = (__half*)msgraw;

    int prep_grid = NN * INC / 2 / 256;   // 6250 >= NB, covers all prep work
    hipMemsetAsync(d_ws, 0xFF, ff_bytes, stream);
    preph_k   <<<prep_grid, 256, 0, stream>>>(W1, W2, x, ei, et, W1f, W2f, xh, ghist);
    rscan_k   <<<1, 1024, 0, stream>>>(ghist, rbase, rngs, chunkrel);
    rscatter_k<<<NB, 256, 0, stream>>>(ei, et, rbase, rsorted);
    relcnt_k  <<<2 * NR, 1024, 0, stream>>>(rsorted, rngs, cnt, rank16);
    drel_k    <<<(NN + 255) / 256, 256, 0, stream>>>(cnt, packed, dhist);
    dprefix_k <<<1, 1024, 0, stream>>>(dhist, rowptr);
    msg1_k    <<<(MAXE + 255) / 256, 256, 0, stream>>>(xh, W1f, rsorted, rank16,
                                                       packed, rowptr, chunkrel, msg1);
    gather1_k <<<NN * 64 / 256, 256, 0, stream>>>(x, root1, b1, msg1, rowptr, hh);
    msg2_k    <<<(MAXE + 255) / 256, 256, 0, stream>>>(hh, W2f, rsorted, rank16,
                                                       packed, rowptr, chunkrel, msg2);
    gather2_k <<<NN * 64 / 256, 256, 0, stream>>>(hh, root2, b2, msg2, rowptr, out);
}